// Round 1
// baseline (154.200 us; speedup 1.0000x reference)
//
#include <hip/hip_runtime.h>

#define WAVE 64

// ---------------------------------------------------------------------------
// Kernel 1: segment sum + count over sorted batch index.
// Each wave owns a contiguous region of nodes. Per 64-element window:
// coalesced float4 loads of x, int loads of batch, segmented suffix-scan via
// shfl_down doubling (valid because batch is sorted => segments contiguous),
// then run-head lanes flush partial sums with atomicAdd.
// ---------------------------------------------------------------------------
__global__ void seg_reduce_kernel(const float4* __restrict__ x,
                                  const int* __restrict__ batch,
                                  float* __restrict__ seg_sum,  // [B*4]
                                  float* __restrict__ seg_cnt,  // [B]
                                  int N, int per_wave) {
    const int wid  = (blockIdx.x * blockDim.x + threadIdx.x) / WAVE;
    const int lane = threadIdx.x & (WAVE - 1);

    long long start = (long long)wid * per_wave;
    long long end   = start + per_wave;
    if (end > N) end = N;
    if (start >= N) return;

    for (long long base = start; base < end; base += WAVE) {
        long long idx = base + lane;
        const bool valid = (idx < end);

        int   seg = valid ? batch[idx] : -1;
        float4 v  = valid ? x[idx] : make_float4(0.f, 0.f, 0.f, 0.f);
        float  c  = valid ? 1.0f : 0.0f;

        // Segmented suffix-sum (doubling). After this, each run-head lane
        // holds the sum of its run within this 64-wide window.
        #pragma unroll
        for (int off = 1; off < WAVE; off <<= 1) {
            int   s2 = __shfl_down(seg, off);
            float vx = __shfl_down(v.x, off);
            float vy = __shfl_down(v.y, off);
            float vz = __shfl_down(v.z, off);
            float vw = __shfl_down(v.w, off);
            float c2 = __shfl_down(c,   off);
            if ((lane + off) < WAVE && s2 == seg) {
                v.x += vx; v.y += vy; v.z += vz; v.w += vw; c += c2;
            }
        }

        int seg_prev = __shfl_up(seg, 1);
        bool head = valid && (lane == 0 || seg_prev != seg);
        if (head) {
            atomicAdd(&seg_sum[(long long)seg * 4 + 0], v.x);
            atomicAdd(&seg_sum[(long long)seg * 4 + 1], v.y);
            atomicAdd(&seg_sum[(long long)seg * 4 + 2], v.z);
            atomicAdd(&seg_sum[(long long)seg * 4 + 3], v.w);
            atomicAdd(&seg_cnt[seg], c);
        }
    }
}

// ---------------------------------------------------------------------------
// Kernel 2: per-graph tiny MLP. h = [u, mean(x)] (5) -> leaky_relu(h@W1+b1)
// -> @W2+b2 -> out[b]. One thread per graph; weights broadcast via cache.
// ---------------------------------------------------------------------------
__global__ void mlp_kernel(const float* __restrict__ u,
                           const float* __restrict__ W1,  // [5*5] row-major (d_in, d_out)
                           const float* __restrict__ b1,  // [5]
                           const float* __restrict__ W2,  // [5]
                           const float* __restrict__ b2,  // [1]
                           const float* __restrict__ seg_sum,
                           const float* __restrict__ seg_cnt,
                           float* __restrict__ out, int B) {
    int b = blockIdx.x * blockDim.x + threadIdx.x;
    if (b >= B) return;

    float c   = seg_cnt[b];
    float inv = (c > 0.5f) ? (1.0f / c) : 0.0f;
    float4 s  = ((const float4*)seg_sum)[b];

    float h[5];
    h[0] = u[b];
    h[1] = s.x * inv;
    h[2] = s.y * inv;
    h[3] = s.z * inv;
    h[4] = s.w * inv;

    float o = b2[0];
    #pragma unroll
    for (int j = 0; j < 5; ++j) {
        float t = b1[j];
        #pragma unroll
        for (int i = 0; i < 5; ++i) t += h[i] * W1[i * 5 + j];
        t = (t > 0.0f) ? t : 0.1f * t;   // leaky_relu, slope 0.1
        o += t * W2[j];
    }
    out[b] = o;
}

extern "C" void kernel_launch(void* const* d_in, const int* in_sizes, int n_in,
                              void* d_out, int out_size, void* d_ws, size_t ws_size,
                              hipStream_t stream) {
    const float* x     = (const float*)d_in[0];  // [N,4]
    const int*   batch = (const int*)  d_in[1];  // [N]
    const float* u     = (const float*)d_in[2];  // [B,1]
    const float* W1    = (const float*)d_in[3];  // [5,5]
    const float* b1    = (const float*)d_in[4];  // [5]
    const float* W2    = (const float*)d_in[5];  // [5,1]
    const float* b2    = (const float*)d_in[6];  // [1]
    float* out = (float*)d_out;

    const int N = in_sizes[0] / 4;
    const int B = out_size;                      // output is [B,1]

    float* seg_sum = (float*)d_ws;               // B*4 floats
    float* seg_cnt = seg_sum + (size_t)B * 4;    // B floats

    // ws is re-poisoned to 0xAA before every launch -> zero our accumulators.
    hipMemsetAsync(d_ws, 0, (size_t)B * 5 * sizeof(float), stream);

    const int threads = 256;
    const int blocks  = 1024;                    // 4096 waves
    const int waves   = blocks * threads / WAVE;
    int per_wave = ((N + waves - 1) / waves + (WAVE - 1)) & ~(WAVE - 1);

    seg_reduce_kernel<<<blocks, threads, 0, stream>>>(
        (const float4*)x, batch, seg_sum, seg_cnt, N, per_wave);

    mlp_kernel<<<(B + 255) / 256, 256, 0, stream>>>(
        u, W1, b1, W2, b2, seg_sum, seg_cnt, out, B);
}

// Round 2
// 148.038 us; speedup vs baseline: 1.0416x; 1.0416x over previous
//
#include <hip/hip_runtime.h>

#define WAVE 64

// ---------------------------------------------------------------------------
// Kernel A: segment start offsets from the sorted batch index.
// seg_start[s] = min{ i : batch[i] >= s }, for s in [0, B]  (seg_start[B] = N).
// Thread i in [0, N] looks at the (batch[i-1], batch[i]] gap and writes all
// starts that fall in it. Every s in [0,B] is written exactly once -> no init
// needed (immune to the 0xAA ws poison).
// ---------------------------------------------------------------------------
__global__ void find_starts_kernel(const int* __restrict__ batch,
                                   int* __restrict__ seg_start,
                                   int N, int B) {
    int i = blockIdx.x * blockDim.x + threadIdx.x;
    if (i > N) return;
    int b_prev = (i == 0) ? -1 : batch[i - 1];
    int b_cur  = (i == N) ? B  : batch[i];
    for (int s = b_prev + 1; s <= b_cur; ++s) seg_start[s] = i;
}

// ---------------------------------------------------------------------------
// Kernel B: one wave per segment. Coalesced float4 accumulation over the
// segment's contiguous rows, wave tree-reduction, then lane 0 computes the
// fused MLP:  h=[u,mean] (5) -> leaky_relu(h@W1+b1) -> @W2+b2 -> out[b].
// No atomics, no shared memory, no workspace reuse beyond seg_start.
// ---------------------------------------------------------------------------
__global__ void __launch_bounds__(256)
seg_mean_mlp_kernel(const float4* __restrict__ x,
                    const int* __restrict__ seg_start,
                    const float* __restrict__ u,
                    const float* __restrict__ W1,   // [5,5] row-major
                    const float* __restrict__ b1,   // [5]
                    const float* __restrict__ W2,   // [5]
                    const float* __restrict__ b2,   // [1]
                    float* __restrict__ out, int B) {
    const int wid  = (blockIdx.x * blockDim.x + threadIdx.x) / WAVE;
    const int lane = threadIdx.x & (WAVE - 1);
    if (wid >= B) return;

    const int start = seg_start[wid];
    const int end   = seg_start[wid + 1];

    float4 acc = make_float4(0.f, 0.f, 0.f, 0.f);
    for (int i = start + lane; i < end; i += WAVE) {
        float4 v = x[i];
        acc.x += v.x; acc.y += v.y; acc.z += v.z; acc.w += v.w;
    }

    // wave tree reduction of 4 floats
    #pragma unroll
    for (int off = 32; off > 0; off >>= 1) {
        acc.x += __shfl_down(acc.x, off);
        acc.y += __shfl_down(acc.y, off);
        acc.z += __shfl_down(acc.z, off);
        acc.w += __shfl_down(acc.w, off);
    }

    if (lane == 0) {
        const int cnt = end - start;
        const float inv = (cnt > 0) ? (1.0f / (float)cnt) : 0.0f;

        float h[5];
        h[0] = u[wid];
        h[1] = acc.x * inv;
        h[2] = acc.y * inv;
        h[3] = acc.z * inv;
        h[4] = acc.w * inv;

        float o = b2[0];
        #pragma unroll
        for (int j = 0; j < 5; ++j) {
            float t = b1[j];
            #pragma unroll
            for (int i = 0; i < 5; ++i) t += h[i] * W1[i * 5 + j];
            t = (t > 0.0f) ? t : 0.1f * t;   // leaky_relu, slope 0.1
            o += t * W2[j];
        }
        out[wid] = o;
    }
}

extern "C" void kernel_launch(void* const* d_in, const int* in_sizes, int n_in,
                              void* d_out, int out_size, void* d_ws, size_t ws_size,
                              hipStream_t stream) {
    const float* x     = (const float*)d_in[0];  // [N,4]
    const int*   batch = (const int*)  d_in[1];  // [N]
    const float* u     = (const float*)d_in[2];  // [B,1]
    const float* W1    = (const float*)d_in[3];  // [5,5]
    const float* b1    = (const float*)d_in[4];  // [5]
    const float* W2    = (const float*)d_in[5];  // [5,1]
    const float* b2    = (const float*)d_in[6];  // [1]
    float* out = (float*)d_out;

    const int N = in_sizes[0] / 4;
    const int B = out_size;                      // output is [B,1]

    int* seg_start = (int*)d_ws;                 // [B+1] ints, fully rewritten each call

    find_starts_kernel<<<(N + 1 + 255) / 256, 256, 0, stream>>>(batch, seg_start, N, B);

    // one wave per segment: B waves = B*64 threads
    const int threads = 256;
    const int blocks  = (B * WAVE + threads - 1) / threads;
    seg_mean_mlp_kernel<<<blocks, threads, 0, stream>>>(
        (const float4*)x, seg_start, u, W1, b1, W2, b2, out, B);
}